// Round 9
// baseline (192.965 us; speedup 1.0000x reference)
//
#include <hip/hip_runtime.h>

// B=16, T=1024, N=1024, D=256, WIN=64
// outputs (flat): R (B,T,2D) = [A@V, Q]   : 8388608 f32
//                 alignments (B,N,T) = A^T: 16777216 f32
//                 max_att (B,T)           : 16384 f32
//
// v8b: one kernel, role-split by blockIdx parity (overlap the 63 MB zero
// stream with the latency-bound attention phases; R7 ran them serialized).
//  - odd blocks (1024): nontemporal-stream zeros over the 960 non-window
//    alignment rows per batch (4 KB contiguous per store round).
//  - even blocks (1024): attn_v7 structure — half-K LDS staging (38 KB,
//    conflict-free b128), direct-global V (L2-hot), R + maxatt + the 64
//    window alignment rows (64B full lines; disjoint from zero role).
// Nontemporal stores use a native clang vector type (HIP float4 is a class
// and rejected by __builtin_nontemporal_store).

#define BB 16
#define TT 1024
#define NN 1024
#define DD 256
#define WIN 64
#define TBLK 16          // queries per attn block
#define NT 256           // 4 waves, 4 queries each

#define R_ELEMS   (16u*1024u*512u)        // 8388608
#define ALN_ELEMS (16u*1024u*1024u)       // 16777216

#define LSTR 132         // LDS row stride (dwords); 132%32==4 -> conflict-free b128

typedef float nt_f4 __attribute__((ext_vector_type(4)));

__device__ __forceinline__ void nt_store4(void* p, float x, float y, float z, float w) {
    nt_f4 v = {x, y, z, w};
    __builtin_nontemporal_store(v, (nt_f4*)p);
}
__device__ __forceinline__ void nt_store4v(void* p, const float4& f) {
    nt_f4 v = {f.x, f.y, f.z, f.w};
    __builtin_nontemporal_store(v, (nt_f4*)p);
}

__global__ __launch_bounds__(NT, 4) void attn_v8(
    const float* __restrict__ Q, const float* __restrict__ K,
    const float* __restrict__ V, const int* __restrict__ prev_in,
    float* __restrict__ out)
{
    __shared__ float ks[WIN * LSTR];        // 33792 B: K half-tile
    __shared__ float p_lds[TBLK][WIN + 4];  // 4352 B : probabilities [t][j]

    float* Rout   = out;
    float* aligns = out + R_ELEMS;
    float* maxatt = out + R_ELEMS + ALN_ELEMS;

    const int tid = threadIdx.x;

    if (blockIdx.x & 1) {
        // ---------------- zero-stream role ----------------
        const int zb    = blockIdx.x >> 1;   // 0..1023
        const int b     = zb >> 6;           // 64 blocks per batch
        const int chunk = zb & 63;           // 15 non-window rows each
        const int prev  = prev_in[b];
        float* base = aligns + (size_t)b * NN * TT;
        #pragma unroll
        for (int r = 0; r < 15; ++r) {
            int idx = chunk * 15 + r;        // 0..959 among non-window rows
            int n   = idx < prev ? idx : idx + WIN;
            nt_store4(base + (size_t)n * TT + tid * 4, 0.f, 0.f, 0.f, 0.f);
        }
        return;
    }

    // ---------------- attention role ----------------
    const int lane = tid & 63;
    const int w    = __builtin_amdgcn_readfirstlane(tid >> 6);  // wave 0..3
    const int ab   = blockIdx.x >> 1;       // 0..1023
    const int b    = ab >> 6;               // 64 attn blocks per batch
    const int t0   = (ab & 63) * TBLK;
    const int prev = prev_in[b];

    const float* qb = Q + ((size_t)b * TT + t0 + 4 * w) * DD;   // wave-uniform base

    // ================= QK^T over two 128-d halves =================
    float acc[4] = {0.f, 0.f, 0.f, 0.f};
    #pragma unroll
    for (int h = 0; h < 2; ++h) {
        if (h) __syncthreads();             // h0 readers done before restage
        const float4* Ksrc = (const float4*)(K + ((size_t)b * NN + prev) * DD + h * 128);
        #pragma unroll
        for (int k = 0; k < 8; ++k) {
            int t4 = tid + k * NT;          // 0..2047 float4 chunks
            int r = t4 >> 5, c = t4 & 31;
            float4 v = Ksrc[(size_t)r * 64 + c];
            *(float4*)&ks[r * LSTR + c * 4] = v;
        }
        __syncthreads();

        const float* qh = qb + h * 128;
        #pragma unroll 8
        for (int d4 = 0; d4 < 32; ++d4) {
            float4 kk = *(const float4*)&ks[lane * LSTR + d4 * 4];  // conflict-free b128
            #pragma unroll
            for (int t = 0; t < 4; ++t) {
                float4 q = ((const float4*)(qh + t * DD))[d4];      // wave-uniform
                acc[t] = fmaf(q.x, kk.x, fmaf(q.y, kk.y, fmaf(q.z, kk.z, fmaf(q.w, kk.w, acc[t]))));
            }
        }
    }

    // ================= softmax + argmax (wave-local), p -> LDS ===========
    #pragma unroll
    for (int t = 0; t < 4; ++t) {
        float v = acc[t] * 0.0625f;         // 1/sqrt(256)

        float m = v;
        #pragma unroll
        for (int off = 32; off; off >>= 1) m = fmaxf(m, __shfl_xor(m, off));

        float e = expf(v - m);
        float s = e;
        #pragma unroll
        for (int off = 32; off; off >>= 1) s += __shfl_xor(s, off);

        p_lds[4 * w + t][lane] = e / s;

        float av = v; int ai = lane;
        #pragma unroll
        for (int off = 32; off; off >>= 1) {
            float ov = __shfl_xor(av, off);
            int   oi = __shfl_xor(ai, off);
            if (ov > av || (ov == av && oi < ai)) { av = ov; ai = oi; }
        }
        if (lane == 0) maxatt[(size_t)b * TT + t0 + 4 * w + t] = (float)(prev + ai);
    }
    __syncthreads();                        // all 16 p rows visible

    // ===== window-row alignment strip: 64 rows x 16 floats (64B lines) ====
    {
        const int j = tid >> 2, cg = tid & 3;
        nt_store4(aligns + ((size_t)b * NN + prev + j) * TT + t0 + cg * 4,
                  p_lds[cg * 4 + 0][j], p_lds[cg * 4 + 1][j],
                  p_lds[cg * 4 + 2][j], p_lds[cg * 4 + 3][j]);
    }

    // ================= PV direct from global (L2-hot V) ==================
    {
        const float4* V4 = (const float4*)(V + ((size_t)b * NN + prev) * DD);
        float4 o[4];
        #pragma unroll
        for (int t = 0; t < 4; ++t) o[t] = make_float4(0.f, 0.f, 0.f, 0.f);

        #pragma unroll 4
        for (int j4 = 0; j4 < WIN / 4; ++j4) {
            float4 p0 = *(const float4*)&p_lds[4 * w + 0][j4 * 4];  // uniform bcast
            float4 p1 = *(const float4*)&p_lds[4 * w + 1][j4 * 4];
            float4 p2 = *(const float4*)&p_lds[4 * w + 2][j4 * 4];
            float4 p3 = *(const float4*)&p_lds[4 * w + 3][j4 * 4];
            float4 v0 = V4[(size_t)(j4 * 4 + 0) * 64 + lane];
            float4 v1 = V4[(size_t)(j4 * 4 + 1) * 64 + lane];
            float4 v2 = V4[(size_t)(j4 * 4 + 2) * 64 + lane];
            float4 v3 = V4[(size_t)(j4 * 4 + 3) * 64 + lane];
            #define ACC4(o_, p_) \
                o_.x = fmaf(p_.x, v0.x, fmaf(p_.y, v1.x, fmaf(p_.z, v2.x, fmaf(p_.w, v3.x, o_.x)))); \
                o_.y = fmaf(p_.x, v0.y, fmaf(p_.y, v1.y, fmaf(p_.z, v2.y, fmaf(p_.w, v3.y, o_.y)))); \
                o_.z = fmaf(p_.x, v0.z, fmaf(p_.y, v1.z, fmaf(p_.z, v2.z, fmaf(p_.w, v3.z, o_.z)))); \
                o_.w = fmaf(p_.x, v0.w, fmaf(p_.y, v1.w, fmaf(p_.z, v2.w, fmaf(p_.w, v3.w, o_.w))));
            ACC4(o[0], p0) ACC4(o[1], p1) ACC4(o[2], p2) ACC4(o[3], p3)
            #undef ACC4
        }

        #pragma unroll
        for (int t = 0; t < 4; ++t) {
            float* Rrow = Rout + ((size_t)b * TT + t0 + 4 * w + t) * (2 * DD);
            nt_store4v(Rrow + lane * 4, o[t]);
            float4 qv = ((const float4*)(qb + t * DD))[lane];
            nt_store4v(Rrow + DD + lane * 4, qv);
        }
    }
}

extern "C" void kernel_launch(void* const* d_in, const int* in_sizes, int n_in,
                              void* d_out, int out_size, void* d_ws, size_t ws_size,
                              hipStream_t stream) {
    const float* Q = (const float*)d_in[0];
    const float* K = (const float*)d_in[1];
    const float* V = (const float*)d_in[2];
    const int* prev = (const int*)d_in[3];
    float* out = (float*)d_out;

    // 1024 attn blocks (even) + 1024 zero-stream blocks (odd), one dispatch.
    attn_v8<<<2 * (BB * TT / TBLK), NT, 0, stream>>>(Q, K, V, prev, out);
}

// Round 10
// 179.344 us; speedup vs baseline: 1.0760x; 1.0760x over previous
//
#include <hip/hip_runtime.h>

// B=16, T=1024, N=1024, D=256, WIN=64
// outputs (flat): R (B,T,2D) = [A@V, Q]   : 8388608 f32
//                 alignments (B,N,T) = A^T: 16777216 f32
//                 max_att (B,T)           : 16384 f32
//
// v10: R7's proven two-kernel split, with the attn kernel rebuilt for
// occupancy: 2 queries/wave -> 8192 waves; 512 thr/block, LDS 38.1 KB ->
// 4 blocks/CU x 8 waves = 32 waves/CU (100% cap). launch_bounds(512,8)
// pins VGPR<=64 (v5's identical 2q shape measured VGPR=32). Half-K LDS
// staging (conflict-free b128, stride 132), V direct from global (L2-hot),
// window-row strip only (64B full lines), nontemporal output stores.
// Zero kernel streams the 63 MB of non-window rows afterwards.

#define BB 16
#define TT 1024
#define NN 1024
#define DD 256
#define WIN 64
#define TBLK 16          // queries per block
#define NT 512           // 8 waves, 2 queries each

#define R_ELEMS   (16u*1024u*512u)        // 8388608
#define ALN_ELEMS (16u*1024u*1024u)       // 16777216

#define LSTR 132         // LDS row stride (dwords); 132%32==4 -> conflict-free b128

typedef float nt_f4 __attribute__((ext_vector_type(4)));

__device__ __forceinline__ void nt_store4(void* p, float x, float y, float z, float w) {
    nt_f4 v = {x, y, z, w};
    __builtin_nontemporal_store(v, (nt_f4*)p);
}
__device__ __forceinline__ void nt_store4v(void* p, const float4& f) {
    nt_f4 v = {f.x, f.y, f.z, f.w};
    __builtin_nontemporal_store(v, (nt_f4*)p);
}

__global__ __launch_bounds__(256) void zero_nonwin(
    float* __restrict__ aligns, const int* __restrict__ prev_in)
{
    const int b     = blockIdx.x >> 6;     // 64 blocks per batch
    const int chunk = blockIdx.x & 63;     // 15 non-window rows each
    const int prev  = prev_in[b];
    float* base = aligns + (size_t)b * NN * TT;
    #pragma unroll
    for (int r = 0; r < 15; ++r) {
        int idx = chunk * 15 + r;          // 0..959 among non-window rows
        int n   = idx < prev ? idx : idx + WIN;
        nt_store4(base + (size_t)n * TT + threadIdx.x * 4, 0.f, 0.f, 0.f, 0.f);
    }
}

__global__ __launch_bounds__(NT, 8) void attn_v10(
    const float* __restrict__ Q, const float* __restrict__ K,
    const float* __restrict__ V, const int* __restrict__ prev_in,
    float* __restrict__ out)
{
    __shared__ float ks[WIN * LSTR];        // 33792 B: K half-tile
    __shared__ float p_lds[TBLK][WIN + 4];  // 4352 B : probabilities [t][j]

    float* Rout   = out;
    float* aligns = out + R_ELEMS;
    float* maxatt = out + R_ELEMS + ALN_ELEMS;

    const int tid  = threadIdx.x;
    const int lane = tid & 63;
    const int w    = __builtin_amdgcn_readfirstlane(tid >> 6);  // wave 0..7
    const int b    = blockIdx.x >> 6;       // 64 blocks per batch
    const int t0   = (blockIdx.x & 63) * TBLK;
    const int prev = prev_in[b];

    const float* qb = Q + ((size_t)b * TT + t0 + 2 * w) * DD;   // wave-uniform base

    // ================= QK^T over two 128-d halves =================
    float acc0 = 0.f, acc1 = 0.f;
    #pragma unroll
    for (int h = 0; h < 2; ++h) {
        if (h) __syncthreads();             // h0 readers done before restage
        const float4* Ksrc = (const float4*)(K + ((size_t)b * NN + prev) * DD + h * 128);
        #pragma unroll
        for (int k = 0; k < 4; ++k) {
            int t4 = tid + k * NT;          // 0..2047 float4 chunks
            int r = t4 >> 5, c = t4 & 31;
            float4 v = Ksrc[(size_t)r * 64 + c];
            *(float4*)&ks[r * LSTR + c * 4] = v;
        }
        __syncthreads();

        const float* qh = qb + h * 128;
        #pragma unroll 8
        for (int d4 = 0; d4 < 32; ++d4) {
            float4 kk = *(const float4*)&ks[lane * LSTR + d4 * 4];  // conflict-free b128
            float4 q0 = ((const float4*)qh)[d4];                    // wave-uniform
            float4 q1 = ((const float4*)(qh + DD))[d4];
            acc0 = fmaf(q0.x, kk.x, fmaf(q0.y, kk.y, fmaf(q0.z, kk.z, fmaf(q0.w, kk.w, acc0))));
            acc1 = fmaf(q1.x, kk.x, fmaf(q1.y, kk.y, fmaf(q1.z, kk.z, fmaf(q1.w, kk.w, acc1))));
        }
    }

    // ================= softmax + argmax (wave-local), p -> LDS ===========
    const int tq0 = 2 * w, tq1 = 2 * w + 1;
    #pragma unroll
    for (int t = 0; t < 2; ++t) {
        float v = (t ? acc1 : acc0) * 0.0625f;   // 1/sqrt(256)

        float m = v;
        #pragma unroll
        for (int off = 32; off; off >>= 1) m = fmaxf(m, __shfl_xor(m, off));

        float e = expf(v - m);
        float s = e;
        #pragma unroll
        for (int off = 32; off; off >>= 1) s += __shfl_xor(s, off);

        p_lds[2 * w + t][lane] = e / s;

        float av = v; int ai = lane;
        #pragma unroll
        for (int off = 32; off; off >>= 1) {
            float ov = __shfl_xor(av, off);
            int   oi = __shfl_xor(ai, off);
            if (ov > av || (ov == av && oi < ai)) { av = ov; ai = oi; }
        }
        if (lane == 0) maxatt[(size_t)b * TT + t0 + 2 * w + t] = (float)(prev + ai);
    }
    __syncthreads();                        // all 16 p rows visible

    // ===== window-row alignment strip: 64 rows x 16 floats (64B lines) ====
    // zero_nonwin never touches these rows -> written exactly once.
    if (tid < 256) {
        const int j = tid >> 2, cg = tid & 3;
        nt_store4(aligns + ((size_t)b * NN + prev + j) * TT + t0 + cg * 4,
                  p_lds[cg * 4 + 0][j], p_lds[cg * 4 + 1][j],
                  p_lds[cg * 4 + 2][j], p_lds[cg * 4 + 3][j]);
    }

    // ================= PV direct from global (L1/L2-hot V) ===============
    // lane = d-chunk (64 x float4 = full 256-d row); own wave's p rows.
    {
        const float4* V4 = (const float4*)(V + ((size_t)b * NN + prev) * DD);
        float4 o0 = make_float4(0.f, 0.f, 0.f, 0.f);
        float4 o1 = make_float4(0.f, 0.f, 0.f, 0.f);

        #pragma unroll 4
        for (int j4 = 0; j4 < WIN / 4; ++j4) {
            float4 p0 = *(const float4*)&p_lds[tq0][j4 * 4];   // uniform bcast
            float4 p1 = *(const float4*)&p_lds[tq1][j4 * 4];
            float4 v0 = V4[(size_t)(j4 * 4 + 0) * 64 + lane];
            float4 v1 = V4[(size_t)(j4 * 4 + 1) * 64 + lane];
            float4 v2 = V4[(size_t)(j4 * 4 + 2) * 64 + lane];
            float4 v3 = V4[(size_t)(j4 * 4 + 3) * 64 + lane];
            #define ACC4(o_, p_) \
                o_.x = fmaf(p_.x, v0.x, fmaf(p_.y, v1.x, fmaf(p_.z, v2.x, fmaf(p_.w, v3.x, o_.x)))); \
                o_.y = fmaf(p_.x, v0.y, fmaf(p_.y, v1.y, fmaf(p_.z, v2.y, fmaf(p_.w, v3.y, o_.y)))); \
                o_.z = fmaf(p_.x, v0.z, fmaf(p_.y, v1.z, fmaf(p_.z, v2.z, fmaf(p_.w, v3.z, o_.z)))); \
                o_.w = fmaf(p_.x, v0.w, fmaf(p_.y, v1.w, fmaf(p_.z, v2.w, fmaf(p_.w, v3.w, o_.w))));
            ACC4(o0, p0) ACC4(o1, p1)
            #undef ACC4
        }

        float* Rrow0 = Rout + ((size_t)b * TT + t0 + tq0) * (2 * DD);
        float* Rrow1 = Rrow0 + 2 * DD;
        nt_store4v(Rrow0 + lane * 4, o0);
        nt_store4v(Rrow1 + lane * 4, o1);
        float4 q0 = ((const float4*)qb)[lane];          // coalesced, L1-hot
        float4 q1 = ((const float4*)(qb + DD))[lane];
        nt_store4v(Rrow0 + DD + lane * 4, q0);
        nt_store4v(Rrow1 + DD + lane * 4, q1);
    }
}

extern "C" void kernel_launch(void* const* d_in, const int* in_sizes, int n_in,
                              void* d_out, int out_size, void* d_ws, size_t ws_size,
                              hipStream_t stream) {
    const float* Q = (const float*)d_in[0];
    const float* K = (const float*)d_in[1];
    const float* V = (const float*)d_in[2];
    const int* prev = (const int*)d_in[3];
    float* out = (float*)d_out;

    // 1) attention: R, maxatt, window alignment rows. 1024 blocks x 512 thr.
    attn_v10<<<BB * TT / TBLK, NT, 0, stream>>>(Q, K, V, prev, out);
    // 2) stream zeros over the 960 non-window rows per batch (63 MB).
    zero_nonwin<<<1024, 256, 0, stream>>>(out + R_ELEMS, prev);
}